// Round 2
// baseline (353.377 us; speedup 1.0000x reference)
//
#include <hip/hip_runtime.h>

#define DI __device__ __forceinline__

typedef unsigned short u16;
typedef unsigned int u32;
typedef float f32x4 __attribute__((ext_vector_type(4)));
typedef short bf16x8 __attribute__((ext_vector_type(8)));
typedef u16 u16x8 __attribute__((ext_vector_type(8)));
typedef u16 u16x4 __attribute__((ext_vector_type(4)));

// ws byte offsets
constexpr size_t OFF_XB = 0;                  // x bf16 [4096][1024]
constexpr size_t OFF_WB = 8388608;            // Wq,Wk,Wv,Wo bf16 4x[1024][1024]
constexpr size_t OFF_QH = 16777216;           // q heads bf16 [B][NH][S][64]
constexpr size_t OFF_KH = 25165824;           // k heads
constexpr size_t OFF_VH = 33554432;           // v heads (pre-transpose)
constexpr size_t OFF_VT = 41943040;           // v transposed [B][NH][64][S]
constexpr size_t OFF_AT = 50331648;           // attn out bf16 [4096][1024]
constexpr size_t OFF_Y  = 58720256;           // y f32 [4096][1024]

DI u16 f2bf(float f) {
  u32 u = __float_as_uint(f);
  u += 0x7FFFu + ((u >> 16) & 1u);   // RNE
  return (u16)(u >> 16);
}
DI float bf2f(u16 h) { return __uint_as_float(((u32)h) << 16); }

typedef __attribute__((address_space(1))) const void gas_t;
typedef __attribute__((address_space(3))) void las_t;
DI void gload_lds16(const void* g, void* l) {
  __builtin_amdgcn_global_load_lds((gas_t*)g, (las_t*)l, 16, 0, 0);
}

// ---------------- fp32 -> bf16 converts ----------------
__global__ __launch_bounds__(256) void cvt_x(const float* __restrict__ src, u16* __restrict__ dst) {
  int i = blockIdx.x * 256 + threadIdx.x;
  const float4* s = (const float4*)src + (size_t)i * 2;
  float4 a = s[0], b = s[1];
  u16x8 o;
  o[0]=f2bf(a.x); o[1]=f2bf(a.y); o[2]=f2bf(a.z); o[3]=f2bf(a.w);
  o[4]=f2bf(b.x); o[5]=f2bf(b.y); o[6]=f2bf(b.z); o[7]=f2bf(b.w);
  *((u16x8*)dst + i) = o;
}

__global__ __launch_bounds__(256) void cvt_w4(const float* __restrict__ w0, const float* __restrict__ w1,
                                              const float* __restrict__ w2, const float* __restrict__ w3,
                                              u16* __restrict__ dst) {
  int z = blockIdx.z;
  const float* src = (z==0)?w0:(z==1)?w1:(z==2)?w2:w3;
  int i = blockIdx.x * 256 + threadIdx.x;
  const float4* s = (const float4*)src + (size_t)i * 2;
  float4 a = s[0], b = s[1];
  u16x8 o;
  o[0]=f2bf(a.x); o[1]=f2bf(a.y); o[2]=f2bf(a.z); o[3]=f2bf(a.w);
  o[4]=f2bf(b.x); o[5]=f2bf(b.y); o[6]=f2bf(b.z); o[7]=f2bf(b.w);
  *((u16x8*)(dst + (size_t)z * 1048576) + i) = o;
}

// ---------------- 128x128 bf16 MFMA GEMM: C = A * W^T (+bias, epilogues) ----------------
template<int MODE>
__global__ __launch_bounds__(256) void gemm128(const u16* __restrict__ A, const u16* __restrict__ Wall,
    const float* __restrict__ b0, const float* __restrict__ b1, const float* __restrict__ b2,
    const float* __restrict__ resid, u16* __restrict__ outH, float* __restrict__ outY)
{
  __shared__ u16 lds[2][4096];   // A-tile [128][32], W-tile [128][32]
  const int z = blockIdx.z;
  const u16* W = Wall + (size_t)z * 1048576;
  const float* bias = (z==0) ? b0 : (z==1) ? b1 : b2;
  const int bx = blockIdx.x, by = blockIdx.y;
  const int tid = threadIdx.x, wave = tid >> 6, lane = tid & 63;
  const int lo = lane & 15, hi = lane >> 4;
  const int wm = wave >> 1, wn = wave & 1;
  f32x4 acc[4][4] = {};
  const u16* Ab = A + (size_t)(by * 128) * 1024;
  const u16* Wb = W + (size_t)(bx * 128) * 1024;
  const int r0 = wave * 32, r1 = wave * 32 + 16;
  const int lrow = lane >> 2, lcol = (lane & 3) * 8;

  for (int kt = 0; kt < 32; ++kt) {
    const int kc = kt * 32;
    gload_lds16(Ab + (size_t)(r0 + lrow) * 1024 + kc + lcol, &lds[0][r0 * 32]);
    gload_lds16(Ab + (size_t)(r1 + lrow) * 1024 + kc + lcol, &lds[0][r1 * 32]);
    gload_lds16(Wb + (size_t)(r0 + lrow) * 1024 + kc + lcol, &lds[1][r0 * 32]);
    gload_lds16(Wb + (size_t)(r1 + lrow) * 1024 + kc + lcol, &lds[1][r1 * 32]);
    __syncthreads();
    bf16x8 af[4], bf[4];
    #pragma unroll
    for (int mi = 0; mi < 4; ++mi) af[mi] = *(const bf16x8*)&lds[0][(wm*64 + mi*16 + lo)*32 + hi*8];
    #pragma unroll
    for (int ni = 0; ni < 4; ++ni) bf[ni] = *(const bf16x8*)&lds[1][(wn*64 + ni*16 + lo)*32 + hi*8];
    #pragma unroll
    for (int mi = 0; mi < 4; ++mi)
      #pragma unroll
      for (int ni = 0; ni < 4; ++ni)
        acc[mi][ni] = __builtin_amdgcn_mfma_f32_16x16x32_bf16(af[mi], bf[ni], acc[mi][ni], 0, 0, 0);
    __syncthreads();
  }

  #pragma unroll
  for (int mi = 0; mi < 4; ++mi) {
    #pragma unroll
    for (int ni = 0; ni < 4; ++ni) {
      const int gn = bx*128 + wn*64 + ni*16 + lo;
      const float bv = bias[gn];
      #pragma unroll
      for (int r = 0; r < 4; ++r) {
        const int gm = by*128 + wm*64 + mi*16 + hi*4 + r;
        float v = acc[mi][ni][r] + bv;
        if (MODE == 0) {
          const int b = gm >> 11, s = gm & 2047, hh = gn >> 6, d = gn & 63;
          outH[(size_t)z * 4194304 + ((((size_t)b*16 + hh)*2048 + s)*64 + d)] = f2bf(v);
        } else {
          const size_t idx = (size_t)gm * 1024 + gn;
          outY[idx] = v + resid[idx];
        }
      }
    }
  }
}

// ---------------- V transpose: [B][NH][S][64] -> [B][NH][64][S] ----------------
__global__ __launch_bounds__(256) void transpose_v(const u16* __restrict__ vh, u16* __restrict__ vT) {
  __shared__ u16 t[64][72];
  const int bh = blockIdx.y, st = blockIdx.x * 64;
  const u16* src = vh + ((size_t)bh * 2048 + st) * 64;
  u16* dst = vT + (size_t)bh * 131072 + st;
  const int tid = threadIdx.x;
  #pragma unroll
  for (int i = 0; i < 4; ++i) {
    int idx = tid + i * 256;
    int r = idx >> 4, c = (idx & 15) * 4;
    *(u16x4*)&t[r][c] = *(const u16x4*)&src[r * 64 + c];
  }
  __syncthreads();
  #pragma unroll
  for (int i = 0; i < 4; ++i) {
    int idx = tid + i * 256;
    int d = idx >> 4, s4 = (idx & 15) * 4;
    u16x4 o;
    o[0] = t[s4+0][d]; o[1] = t[s4+1][d]; o[2] = t[s4+2][d]; o[3] = t[s4+3][d];
    *(u16x4*)&dst[(size_t)d * 2048 + s4] = o;
  }
}

// ---------------- fused attention (restructured) ----------------
// grid (128, 32): x = q-tile (16 rows), y = b*16+h. 512 threads (8 waves),
// wave w owns k-strip [w*256, (w+1)*256).
// LDS: es[16 q][2048 k] bf16, row stride 4096B, byte ^= ((q&7)<<4) swizzle = 64KiB,
//      then reduce arrays. Total 66752 B -> 2 blocks/CU.
// Pass 1: S^T = mfma(K, Q) -> lane holds s[k=hi*4+r][q=lo] (q fixed per lane!);
//         es=exp(s/8+mask) -> packed b64 write to es[q][k]; accumulate L.
// Pass 2: read P^T frag as one b128 (k contiguous), ep=exp(es*rL) on the fly,
//         accumulate S2 alongside; O^T = mfma(V^T, P^T) for ep and ep^2.
// Epilogue: D = S2+1e-6; attn = (0.5/D)*O1 + (0.25/D^2)*O2 (sigmoid(x)~0.5+x/4).
__global__ __launch_bounds__(512, 4) void attn_fused(
    const u16* __restrict__ qh, const u16* __restrict__ kh, const u16* __restrict__ vT,
    const float* __restrict__ mask, u16* __restrict__ attnb)
{
  extern __shared__ char smem[];
  float* redL  = (float*)(smem + 65536);   // [128]
  float* redRL = (float*)(smem + 66048);   // [16]
  float* redS2 = (float*)(smem + 66112);   // [128]
  float* c12   = (float*)(smem + 66624);   // [32]
  const int bh = blockIdx.y, qt = blockIdx.x;
  const int tid = threadIdx.x, w = tid >> 6, lane = tid & 63;
  const int lo = lane & 15, hi = lane >> 4;
  const u16* Q  = qh + ((size_t)bh * 2048 + qt * 16) * 64;
  const u16* Kp = kh + (size_t)bh * 131072;
  const u16* Vp = vT + (size_t)bh * 131072;
  const float* mrow = mask + (size_t)(bh >> 4) * 2048;
  const int swz = (lo & 7) << 4;

  // Q fragment: lane holds Q[q=lo][d=hi*8+j] (B-operand of swapped QK^T)
  bf16x8 qa0 = *(const bf16x8*)&Q[lo * 64 + hi * 8];
  bf16x8 qa1 = *(const bf16x8*)&Q[lo * 64 + 32 + hi * 8];

  // ---- pass 1: S^T -> es LDS [q][k], accumulate L ----
  float Lp = 0.f;
  #pragma unroll 2
  for (int kt = 0; kt < 16; ++kt) {
    const int k0 = w * 256 + kt * 16;
    const u16* Krow = &Kp[(size_t)(k0 + lo) * 64 + hi * 8];
    bf16x8 kb0 = *(const bf16x8*)&Krow[0];
    bf16x8 kb1 = *(const bf16x8*)&Krow[32];
    float4 mk4 = *(const float4*)&mrow[k0 + hi * 4];
    f32x4 a = {0.f, 0.f, 0.f, 0.f};
    a = __builtin_amdgcn_mfma_f32_16x16x32_bf16(kb0, qa0, a, 0, 0, 0);
    a = __builtin_amdgcn_mfma_f32_16x16x32_bf16(kb1, qa1, a, 0, 0, 0);
    float e0 = __expf(a[0] * 0.125f + mk4.x);
    float e1 = __expf(a[1] * 0.125f + mk4.y);
    float e2 = __expf(a[2] * 0.125f + mk4.z);
    float e3 = __expf(a[3] * 0.125f + mk4.w);
    Lp += (e0 + e1) + (e2 + e3);
    uint2 pk;
    pk.x = (u32)f2bf(e0) | ((u32)f2bf(e1) << 16);
    pk.y = (u32)f2bf(e2) | ((u32)f2bf(e3) << 16);
    *(uint2*)(smem + lo * 4096 + ((((k0 + hi * 4) * 2)) ^ swz)) = pk;
  }
  Lp += __shfl_xor(Lp, 16);
  Lp += __shfl_xor(Lp, 32);
  if (lane < 16) redL[w * 16 + lane] = Lp;
  __syncthreads();
  if (tid < 16) {
    float L = 0.f;
    #pragma unroll
    for (int ww = 0; ww < 8; ++ww) L += redL[ww * 16 + tid];
    redRL[tid] = 1.0f / L;
  }
  __syncthreads();
  const float rq = redRL[lo];

  // ---- pass 2: ep on the fly, O1 = sum ep*v, O2 = sum ep^2*v, S2 alongside ----
  f32x4 o1[4] = {}, o2[4] = {};
  float s2 = 0.f;
  #pragma unroll 2
  for (int ks = 0; ks < 8; ++ks) {
    const int kb = w * 256 + ks * 32;
    bf16x8 vb[4];
    #pragma unroll
    for (int ni = 0; ni < 4; ++ni)
      vb[ni] = *(const bf16x8*)&Vp[(size_t)(ni * 16 + lo) * 2048 + kb + hi * 8];
    u16x8 pv = *(const u16x8*)(smem + lo * 4096 + ((kb * 2 + hi * 16) ^ swz));
    bf16x8 a1, a2;
    #pragma unroll
    for (int j = 0; j < 8; ++j) {
      const float e = __expf(bf2f(pv[j]) * rq);
      s2 += e;
      a1[j] = (short)f2bf(e);
      a2[j] = (short)f2bf(e * e);
    }
    #pragma unroll
    for (int ni = 0; ni < 4; ++ni) {
      o1[ni] = __builtin_amdgcn_mfma_f32_16x16x32_bf16(vb[ni], a1, o1[ni], 0, 0, 0);
      o2[ni] = __builtin_amdgcn_mfma_f32_16x16x32_bf16(vb[ni], a2, o2[ni], 0, 0, 0);
    }
  }
  s2 += __shfl_xor(s2, 16);
  s2 += __shfl_xor(s2, 32);
  if (lane < 16) redS2[w * 16 + lane] = s2;
  __syncthreads();   // all pass-2 es reads complete; es region reusable
  if (tid < 16) {
    float S2 = 0.f;
    #pragma unroll
    for (int ww = 0; ww < 8; ++ww) S2 += redS2[ww * 16 + tid];
    const float rD = 1.0f / (S2 + 1e-6f);
    c12[tid] = 0.5f * rD;
    c12[16 + tid] = 0.25f * rD * rD;
  }
  // stage per-wave O^T partials: region w: [2][16 q][64 d] f32, byte col ^ ((q&7)<<4)
  {
    char* ow = smem + w * 8192;
    #pragma unroll
    for (int ni = 0; ni < 4; ++ni) {
      const int d0 = ni * 16 + hi * 4;   // o1[ni][r] holds d = d0 + r (consecutive)
      *(f32x4*)(ow + lo * 256 + ((d0 * 4) ^ swz)) = o1[ni];
      *(f32x4*)(ow + 4096 + lo * 256 + ((d0 * 4) ^ swz)) = o2[ni];
    }
  }
  __syncthreads();
  // combine 8 wave partials, scale, write bf16
  if (tid < 256) {
    const int q = tid >> 4, d0 = (tid & 15) * 4;
    const int qs = (q & 7) << 4;
    f32x4 v1 = {0.f, 0.f, 0.f, 0.f}, v2 = {0.f, 0.f, 0.f, 0.f};
    #pragma unroll
    for (int ww = 0; ww < 8; ++ww) {
      const char* owp = smem + ww * 8192 + q * 256 + ((d0 * 4) ^ qs);
      f32x4 t1 = *(const f32x4*)owp;
      f32x4 t2 = *(const f32x4*)(owp + 4096);
      v1 += t1;
      v2 += t2;
    }
    const float cc1 = c12[q], cc2 = c12[16 + q];
    u16x4 o;
    o[0] = f2bf(cc1 * v1[0] + cc2 * v2[0]);
    o[1] = f2bf(cc1 * v1[1] + cc2 * v2[1]);
    o[2] = f2bf(cc1 * v1[2] + cc2 * v2[2]);
    o[3] = f2bf(cc1 * v1[3] + cc2 * v2[3]);
    u16* arow = attnb + ((size_t)(bh >> 4) * 2048 + qt * 16 + q) * 1024 + (bh & 15) * 64 + d0;
    *(u16x4*)arow = o;
  }
}

// ---------------- LayerNorm with Quake-III inv-sqrt replication ----------------
__global__ __launch_bounds__(256) void layernorm_k(const float* __restrict__ y, const float* __restrict__ nw,
                                                   const float* __restrict__ nb, float* __restrict__ out)
{
  const int row = blockIdx.x;
  const float* yr = y + (size_t)row * 1024;
  const int tid = threadIdx.x;
  float4 x = *(const float4*)&yr[tid * 4];
  float s  = x.x + x.y + x.z + x.w;
  float s2 = x.x*x.x + x.y*x.y + x.z*x.z + x.w*x.w;
  #pragma unroll
  for (int m = 1; m < 64; m <<= 1) { s += __shfl_xor(s, m); s2 += __shfl_xor(s2, m); }
  __shared__ float rs[4], rs2[4];
  const int wv = tid >> 6;
  if ((tid & 63) == 0) { rs[wv] = s; rs2[wv] = s2; }
  __syncthreads();
  s  = rs[0] + rs[1] + rs[2] + rs[3];
  s2 = rs2[0] + rs2[1] + rs2[2] + rs2[3];
  const float mean = s * (1.0f / 1024.0f);
  const float var  = s2 * (1.0f / 1024.0f) - mean * mean;
  const float r = var + 1e-5f;
  int ib = __float_as_int(r);
  ib = 1597463007 - (ib >> 1);
  const float y0 = __int_as_float(ib);
  const float inv = y0 * (1.5f - 0.5f * r * y0 * y0);
  float4 w4 = *(const float4*)&nw[tid * 4];
  float4 b4 = *(const float4*)&nb[tid * 4];
  float4 o;
  o.x = w4.x * ((x.x - mean) * inv) + b4.x;
  o.y = w4.y * ((x.y - mean) * inv) + b4.y;
  o.z = w4.z * ((x.z - mean) * inv) + b4.z;
  o.w = w4.w * ((x.w - mean) * inv) + b4.w;
  *(float4*)&out[(size_t)row * 1024 + tid * 4] = o;
}

extern "C" void kernel_launch(void* const* d_in, const int* in_sizes, int n_in,
                              void* d_out, int out_size, void* d_ws, size_t ws_size,
                              hipStream_t stream)
{
  const float* x    = (const float*)d_in[0];
  const float* mask = (const float*)d_in[1];
  const float* Wq   = (const float*)d_in[2];
  const float* bq   = (const float*)d_in[3];
  const float* Wk   = (const float*)d_in[4];
  const float* bk   = (const float*)d_in[5];
  const float* Wv   = (const float*)d_in[6];
  const float* bv   = (const float*)d_in[7];
  const float* Wo   = (const float*)d_in[8];
  const float* bo   = (const float*)d_in[9];
  const float* nw   = (const float*)d_in[10];
  const float* nb   = (const float*)d_in[11];
  float* out = (float*)d_out;
  char* ws = (char*)d_ws;
  u16* xb    = (u16*)(ws + OFF_XB);
  u16* wb    = (u16*)(ws + OFF_WB);
  u16* qhp   = (u16*)(ws + OFF_QH);
  u16* vhp   = (u16*)(ws + OFF_VH);
  u16* vT    = (u16*)(ws + OFF_VT);
  u16* attnb = (u16*)(ws + OFF_AT);
  float* y   = (float*)(ws + OFF_Y);
  (void)in_sizes; (void)n_in; (void)out_size; (void)ws_size;

  hipFuncSetAttribute((const void*)attn_fused, hipFuncAttributeMaxDynamicSharedMemorySize, 66752);

  cvt_x<<<2048, 256, 0, stream>>>(x, xb);
  cvt_w4<<<dim3(512, 1, 4), 256, 0, stream>>>(Wq, Wk, Wv, Wo, wb);
  gemm128<0><<<dim3(8, 32, 3), 256, 0, stream>>>(xb, wb, bq, bk, bv, nullptr, qhp, nullptr);
  transpose_v<<<dim3(32, 32), 256, 0, stream>>>(vhp, vT);
  attn_fused<<<dim3(128, 32), 512, 66752, stream>>>(qhp, (u16*)(ws + OFF_KH), vT, mask, attnb);
  gemm128<1><<<dim3(8, 32, 1), 256, 0, stream>>>(attnb, wb + 3*1048576, bo, nullptr, nullptr, x, nullptr, y);
  layernorm_k<<<4096, 256, 0, stream>>>(y, nw, nb, out);
}

// Round 4
// 223.351 us; speedup vs baseline: 1.5822x; 1.5822x over previous
//
#include <hip/hip_runtime.h>

#define DI __device__ __forceinline__

typedef unsigned short u16;
typedef unsigned int u32;
typedef float f32x4 __attribute__((ext_vector_type(4)));
typedef short bf16x8 __attribute__((ext_vector_type(8)));
typedef u16 u16x8 __attribute__((ext_vector_type(8)));
typedef u16 u16x4 __attribute__((ext_vector_type(4)));

// ws byte offsets
constexpr size_t OFF_XB = 0;                  // x bf16 [4096][1024]
constexpr size_t OFF_WB = 8388608;            // Wq,Wk,Wv,Wo bf16 4x[1024][1024]
constexpr size_t OFF_QH = 16777216;           // q heads bf16 [B][NH][S][64]
constexpr size_t OFF_KH = 25165824;           // k heads
constexpr size_t OFF_VH = 33554432;           // v heads (pre-transpose)
constexpr size_t OFF_VT = 41943040;           // v transposed [B][NH][64][S]
constexpr size_t OFF_AT = 50331648;           // attn out bf16 [4096][1024]
constexpr size_t OFF_Y  = 58720256;           // y f32 [4096][1024]

DI u16 f2bf(float f) {
  u32 u = __float_as_uint(f);
  u += 0x7FFFu + ((u >> 16) & 1u);   // RNE
  return (u16)(u >> 16);
}
DI float bf2f(u16 h) { return __uint_as_float(((u32)h) << 16); }

typedef __attribute__((address_space(1))) const void gas_t;
typedef __attribute__((address_space(3))) void las_t;
DI void gload_lds16(const void* g, void* l) {
  __builtin_amdgcn_global_load_lds((gas_t*)g, (las_t*)l, 16, 0, 0);
}

// swizzle: LDS 16B-chunk index XOR, computed from tile row. Keeps every
// fragment ds_read_b128 <=2-way bank-conflicted while LDS stays linear
// (global source column is pre-XOR'd at staging per m173 pattern).
DI int fswz(int row) {
  return (row & 1) | ((((row >> 1) ^ (row >> 3)) & 1) << 1)
                   | ((((row >> 2) ^ (row >> 4)) & 1) << 2);
}

// ---------------- fp32 -> bf16 converts ----------------
__global__ __launch_bounds__(256) void cvt_x(const float* __restrict__ src, u16* __restrict__ dst) {
  int i = blockIdx.x * 256 + threadIdx.x;
  const float4* s = (const float4*)src + (size_t)i * 2;
  float4 a = s[0], b = s[1];
  u16x8 o;
  o[0]=f2bf(a.x); o[1]=f2bf(a.y); o[2]=f2bf(a.z); o[3]=f2bf(a.w);
  o[4]=f2bf(b.x); o[5]=f2bf(b.y); o[6]=f2bf(b.z); o[7]=f2bf(b.w);
  *((u16x8*)dst + i) = o;
}

__global__ __launch_bounds__(256) void cvt_w4(const float* __restrict__ w0, const float* __restrict__ w1,
                                              const float* __restrict__ w2, const float* __restrict__ w3,
                                              u16* __restrict__ dst) {
  int z = blockIdx.z;
  const float* src = (z==0)?w0:(z==1)?w1:(z==2)?w2:w3;
  int i = blockIdx.x * 256 + threadIdx.x;
  const float4* s = (const float4*)src + (size_t)i * 2;
  float4 a = s[0], b = s[1];
  u16x8 o;
  o[0]=f2bf(a.x); o[1]=f2bf(a.y); o[2]=f2bf(a.z); o[3]=f2bf(a.w);
  o[4]=f2bf(b.x); o[5]=f2bf(b.y); o[6]=f2bf(b.z); o[7]=f2bf(b.w);
  *((u16x8*)(dst + (size_t)z * 1048576) + i) = o;
}

// ---------------- 128x128 bf16 MFMA GEMM: C = A * W^T (+bias, epilogues) ----------------
template<int MODE>
__global__ __launch_bounds__(256) void gemm128(const u16* __restrict__ A, const u16* __restrict__ Wall,
    const float* __restrict__ b0, const float* __restrict__ b1, const float* __restrict__ b2,
    const float* __restrict__ resid, u16* __restrict__ outH, float* __restrict__ outY)
{
  __shared__ u16 lds[2][4096];   // A-tile [128][32], W-tile [128][32]
  const int z = blockIdx.z;
  const u16* W = Wall + (size_t)z * 1048576;
  const float* bias = (z==0) ? b0 : (z==1) ? b1 : b2;
  const int bx = blockIdx.x, by = blockIdx.y;
  const int tid = threadIdx.x, wave = tid >> 6, lane = tid & 63;
  const int lo = lane & 15, hi = lane >> 4;
  const int wm = wave >> 1, wn = wave & 1;
  f32x4 acc[4][4] = {};
  const u16* Ab = A + (size_t)(by * 128) * 1024;
  const u16* Wb = W + (size_t)(bx * 128) * 1024;
  const int r0 = wave * 32, r1 = wave * 32 + 16;
  const int lrow = lane >> 2, lcol = (lane & 3) * 8;

  for (int kt = 0; kt < 32; ++kt) {
    const int kc = kt * 32;
    gload_lds16(Ab + (size_t)(r0 + lrow) * 1024 + kc + lcol, &lds[0][r0 * 32]);
    gload_lds16(Ab + (size_t)(r1 + lrow) * 1024 + kc + lcol, &lds[0][r1 * 32]);
    gload_lds16(Wb + (size_t)(r0 + lrow) * 1024 + kc + lcol, &lds[1][r0 * 32]);
    gload_lds16(Wb + (size_t)(r1 + lrow) * 1024 + kc + lcol, &lds[1][r1 * 32]);
    __syncthreads();
    bf16x8 af[4], bf[4];
    #pragma unroll
    for (int mi = 0; mi < 4; ++mi) af[mi] = *(const bf16x8*)&lds[0][(wm*64 + mi*16 + lo)*32 + hi*8];
    #pragma unroll
    for (int ni = 0; ni < 4; ++ni) bf[ni] = *(const bf16x8*)&lds[1][(wn*64 + ni*16 + lo)*32 + hi*8];
    #pragma unroll
    for (int mi = 0; mi < 4; ++mi)
      #pragma unroll
      for (int ni = 0; ni < 4; ++ni)
        acc[mi][ni] = __builtin_amdgcn_mfma_f32_16x16x32_bf16(af[mi], bf[ni], acc[mi][ni], 0, 0, 0);
    __syncthreads();
  }

  #pragma unroll
  for (int mi = 0; mi < 4; ++mi) {
    #pragma unroll
    for (int ni = 0; ni < 4; ++ni) {
      const int gn = bx*128 + wn*64 + ni*16 + lo;
      const float bv = bias[gn];
      #pragma unroll
      for (int r = 0; r < 4; ++r) {
        const int gm = by*128 + wm*64 + mi*16 + hi*4 + r;
        float v = acc[mi][ni][r] + bv;
        if (MODE == 0) {
          const int b = gm >> 11, s = gm & 2047, hh = gn >> 6, d = gn & 63;
          outH[(size_t)z * 4194304 + ((((size_t)b*16 + hh)*2048 + s)*64 + d)] = f2bf(v);
        } else {
          const size_t idx = (size_t)gm * 1024 + gn;
          outY[idx] = v + resid[idx];
        }
      }
    }
  }
}

// ---------------- V transpose: [B][NH][S][64] -> [B][NH][64][S] ----------------
__global__ __launch_bounds__(256) void transpose_v(const u16* __restrict__ vh, u16* __restrict__ vT) {
  __shared__ u16 t[64][72];
  const int bh = blockIdx.y, st = blockIdx.x * 64;
  const u16* src = vh + ((size_t)bh * 2048 + st) * 64;
  u16* dst = vT + (size_t)bh * 131072 + st;
  const int tid = threadIdx.x;
  #pragma unroll
  for (int i = 0; i < 4; ++i) {
    int idx = tid + i * 256;
    int r = idx >> 4, c = (idx & 15) * 4;
    *(u16x4*)&t[r][c] = *(const u16x4*)&src[r * 64 + c];
  }
  __syncthreads();
  #pragma unroll
  for (int i = 0; i < 4; ++i) {
    int idx = tid + i * 256;
    int d = idx >> 4, s4 = (idx & 15) * 4;
    u16x4 o;
    o[0] = t[s4+0][d]; o[1] = t[s4+1][d]; o[2] = t[s4+2][d]; o[3] = t[s4+3][d];
    *(u16x4*)&dst[(size_t)d * 2048 + s4] = o;
  }
}

// ---------------- fused attention: 2-sweep, K/V staged in LDS, zero score storage ----------------
// grid (16, 32): x = q-tile (128 rows), y = bh. 512 threads = 8 waves x 16 q-rows.
// LDS: K tile [64 k][64 d] + V^T tile [64 d][64 k], both double-buffered = 32KB.
// Sweep 1: QK^T (swapped, permuted k-rows), L[q] += exp(s/8+mask); per-lane only.
// Sweep 2: recompute QK^T; ep=exp(es*rL) -> directly the PV B-frag (permutation
//   makes output lane-layout == B-frag layout); accumulate O1=sum ep*V, O2=sum ep^2*V,
//   S2=sum ep. Epilogue: attn = (0.5/D)*O1 + (0.25/D^2)*O2, D=S2+1e-6.
// NOTE (R3 bug): double-buffer stride is 4096 u16 — index Kt[buf]/Vt[buf] directly.
__global__ __launch_bounds__(512, 4) void attn_fused(
    const u16* __restrict__ qh, const u16* __restrict__ kh, const u16* __restrict__ vT,
    const float* __restrict__ mask, u16* __restrict__ attnb)
{
  __shared__ u16 Kt[2][4096];
  __shared__ u16 Vt[2][4096];
  const int bh = blockIdx.y, qt = blockIdx.x;
  const int tid = threadIdx.x, w = tid >> 6, lane = tid & 63;
  const int lo = lane & 15, hi = lane >> 4;
  const int a = lane & 3, g = (lane >> 2) & 3;
  const u16* Qg = qh + ((size_t)bh * 2048 + qt * 128 + w * 16) * 64;
  const u16* Kp = kh + (size_t)bh * 131072;
  const u16* Vp = vT + (size_t)bh * 131072;
  const float* mrow = mask + (size_t)(bh >> 4) * 2048;

  // Q fragment (B-operand of swapped QK^T): lane holds Q[q=lo][d=hi*8+j]
  const bf16x8 qa0 = *(const bf16x8*)&Qg[lo * 64 + hi * 8];
  const bf16x8 qa1 = *(const bf16x8*)&Qg[lo * 64 + 32 + hi * 8];

  // staging source pointers (global col pre-XOR'd so LDS stays linear)
  const int sr = tid >> 3, sc = tid & 7;
  const u16* Ks = Kp + (size_t)sr * 64 + ((sc ^ fswz(sr)) * 8);
  const u16* Vs = Vp + (size_t)sr * 2048 + ((sc ^ fswz(sr)) * 8);

  // read-side swizzle bases
  const int fr0 = (a & 1) | ((((a >> 1) ^ g) & 1) << 1) | (((g >> 1) & 1) << 2);
  const int fv0 = (lo & 1) | ((((lo >> 1) ^ (lo >> 3)) & 1) << 1) | (((lo >> 2) & 1) << 2);
  const int lrowBase = g * 8 + a;   // permuted k-row: + t*4 + kc2*32

  // ================= sweep 1: L =================
  float Lp = 0.f;
  gload_lds16(Ks, &Kt[0][w * 512]);
  __syncthreads();
  for (int n = 0; n < 32; ++n) {
    if (n < 31) gload_lds16(Ks + (size_t)(n + 1) * 4096, &Kt[(n + 1) & 1][w * 512]);
    const char* KT = (const char*)&Kt[n & 1][0];
    #pragma unroll
    for (int kc2 = 0; kc2 < 2; ++kc2) {
      #pragma unroll
      for (int t = 0; t < 2; ++t) {
        const int lrow = kc2 * 32 + lrowBase + t * 4;
        const int fr = fr0 ^ (t << 2);
        const char* rp = KT + lrow * 128;
        bf16x8 kb0 = *(const bf16x8*)(rp + ((hi ^ fr) << 4));
        bf16x8 kb1 = *(const bf16x8*)(rp + (((4 + hi) ^ fr) << 4));
        f32x4 acc = {0.f, 0.f, 0.f, 0.f};
        acc = __builtin_amdgcn_mfma_f32_16x16x32_bf16(kb0, qa0, acc, 0, 0, 0);
        acc = __builtin_amdgcn_mfma_f32_16x16x32_bf16(kb1, qa1, acc, 0, 0, 0);
        const float4 mk = *(const float4*)&mrow[n * 64 + kc2 * 32 + hi * 8 + t * 4];
        float e0 = __expf(acc[0] * 0.125f + mk.x);
        float e1 = __expf(acc[1] * 0.125f + mk.y);
        float e2 = __expf(acc[2] * 0.125f + mk.z);
        float e3 = __expf(acc[3] * 0.125f + mk.w);
        Lp += (e0 + e1) + (e2 + e3);
      }
    }
    __syncthreads();
  }
  // L[q=lo] = sum over hi groups (per-lane, no LDS)
  Lp += __shfl_xor(Lp, 16);
  Lp += __shfl_xor(Lp, 32);
  const float rq = 1.0f / Lp;

  // ================= sweep 2: O1, O2, S2 =================
  f32x4 o1[4] = {}, o2[4] = {};
  float S2p = 0.f;
  gload_lds16(Ks, &Kt[0][w * 512]);
  gload_lds16(Vs, &Vt[0][w * 512]);
  __syncthreads();
  for (int n = 0; n < 32; ++n) {
    if (n < 31) {
      gload_lds16(Ks + (size_t)(n + 1) * 4096, &Kt[(n + 1) & 1][w * 512]);
      gload_lds16(Vs + (size_t)(n + 1) * 64,   &Vt[(n + 1) & 1][w * 512]);
    }
    const char* KT = (const char*)&Kt[n & 1][0];
    const char* VT = (const char*)&Vt[n & 1][0];
    #pragma unroll
    for (int kc2 = 0; kc2 < 2; ++kc2) {
      bf16x8 a1, a2;
      #pragma unroll
      for (int t = 0; t < 2; ++t) {
        const int lrow = kc2 * 32 + lrowBase + t * 4;
        const int fr = fr0 ^ (t << 2);
        const char* rp = KT + lrow * 128;
        bf16x8 kb0 = *(const bf16x8*)(rp + ((hi ^ fr) << 4));
        bf16x8 kb1 = *(const bf16x8*)(rp + (((4 + hi) ^ fr) << 4));
        f32x4 acc = {0.f, 0.f, 0.f, 0.f};
        acc = __builtin_amdgcn_mfma_f32_16x16x32_bf16(kb0, qa0, acc, 0, 0, 0);
        acc = __builtin_amdgcn_mfma_f32_16x16x32_bf16(kb1, qa1, acc, 0, 0, 0);
        const float4 mk = *(const float4*)&mrow[n * 64 + kc2 * 32 + hi * 8 + t * 4];
        #pragma unroll
        for (int r = 0; r < 4; ++r) {
          const float mkr = (r == 0) ? mk.x : (r == 1) ? mk.y : (r == 2) ? mk.z : mk.w;
          const float es = __expf(acc[r] * 0.125f + mkr);
          const float e  = __expf(es * rq);
          S2p += e;
          a1[t * 4 + r] = (short)f2bf(e);
          a2[t * 4 + r] = (short)f2bf(e * e);
        }
      }
      #pragma unroll
      for (int ni = 0; ni < 4; ++ni) {
        const int d = ni * 16 + lo;
        const int fv = fv0 ^ ((ni & 1) << 2);
        bf16x8 vb = *(const bf16x8*)(VT + d * 128 + ((((kc2 << 2) + hi) ^ fv) << 4));
        o1[ni] = __builtin_amdgcn_mfma_f32_16x16x32_bf16(vb, a1, o1[ni], 0, 0, 0);
        o2[ni] = __builtin_amdgcn_mfma_f32_16x16x32_bf16(vb, a2, o2[ni], 0, 0, 0);
      }
    }
    __syncthreads();
  }

  // ================= epilogue (per-lane; q = lo for both S2 and O^T cols) =================
  S2p += __shfl_xor(S2p, 16);
  S2p += __shfl_xor(S2p, 32);
  const float rD = 1.0f / (S2p + 1e-6f);
  const float c1 = 0.5f * rD, c2 = 0.25f * rD * rD;
  u16* arow = attnb + ((size_t)(bh >> 4) * 2048 + qt * 128 + w * 16 + lo) * 1024 + (bh & 15) * 64;
  #pragma unroll
  for (int ni = 0; ni < 4; ++ni) {
    u16x4 ov;
    #pragma unroll
    for (int r = 0; r < 4; ++r) ov[r] = f2bf(c1 * o1[ni][r] + c2 * o2[ni][r]);
    *(u16x4*)&arow[ni * 16 + hi * 4] = ov;
  }
}

// ---------------- LayerNorm with Quake-III inv-sqrt replication ----------------
__global__ __launch_bounds__(256) void layernorm_k(const float* __restrict__ y, const float* __restrict__ nw,
                                                   const float* __restrict__ nb, float* __restrict__ out)
{
  const int row = blockIdx.x;
  const float* yr = y + (size_t)row * 1024;
  const int tid = threadIdx.x;
  float4 x = *(const float4*)&yr[tid * 4];
  float s  = x.x + x.y + x.z + x.w;
  float s2 = x.x*x.x + x.y*x.y + x.z*x.z + x.w*x.w;
  #pragma unroll
  for (int m = 1; m < 64; m <<= 1) { s += __shfl_xor(s, m); s2 += __shfl_xor(s2, m); }
  __shared__ float rs[4], rs2[4];
  const int wv = tid >> 6;
  if ((tid & 63) == 0) { rs[wv] = s; rs2[wv] = s2; }
  __syncthreads();
  s  = rs[0] + rs[1] + rs[2] + rs[3];
  s2 = rs2[0] + rs2[1] + rs2[2] + rs2[3];
  const float mean = s * (1.0f / 1024.0f);
  const float var  = s2 * (1.0f / 1024.0f) - mean * mean;
  const float r = var + 1e-5f;
  int ib = __float_as_int(r);
  ib = 1597463007 - (ib >> 1);
  const float y0 = __int_as_float(ib);
  const float inv = y0 * (1.5f - 0.5f * r * y0 * y0);
  float4 w4 = *(const float4*)&nw[tid * 4];
  float4 b4 = *(const float4*)&nb[tid * 4];
  float4 o;
  o.x = w4.x * ((x.x - mean) * inv) + b4.x;
  o.y = w4.y * ((x.y - mean) * inv) + b4.y;
  o.z = w4.z * ((x.z - mean) * inv) + b4.z;
  o.w = w4.w * ((x.w - mean) * inv) + b4.w;
  *(float4*)&out[(size_t)row * 1024 + tid * 4] = o;
}

extern "C" void kernel_launch(void* const* d_in, const int* in_sizes, int n_in,
                              void* d_out, int out_size, void* d_ws, size_t ws_size,
                              hipStream_t stream)
{
  const float* x    = (const float*)d_in[0];
  const float* mask = (const float*)d_in[1];
  const float* Wq   = (const float*)d_in[2];
  const float* bq   = (const float*)d_in[3];
  const float* Wk   = (const float*)d_in[4];
  const float* bk   = (const float*)d_in[5];
  const float* Wv   = (const float*)d_in[6];
  const float* bv   = (const float*)d_in[7];
  const float* Wo   = (const float*)d_in[8];
  const float* bo   = (const float*)d_in[9];
  const float* nw   = (const float*)d_in[10];
  const float* nb   = (const float*)d_in[11];
  float* out = (float*)d_out;
  char* ws = (char*)d_ws;
  u16* xb    = (u16*)(ws + OFF_XB);
  u16* wb    = (u16*)(ws + OFF_WB);
  u16* qhp   = (u16*)(ws + OFF_QH);
  u16* vhp   = (u16*)(ws + OFF_VH);
  u16* vT    = (u16*)(ws + OFF_VT);
  u16* attnb = (u16*)(ws + OFF_AT);
  float* y   = (float*)(ws + OFF_Y);
  (void)in_sizes; (void)n_in; (void)out_size; (void)ws_size;

  cvt_x<<<2048, 256, 0, stream>>>(x, xb);
  cvt_w4<<<dim3(512, 1, 4), 256, 0, stream>>>(Wq, Wk, Wv, Wo, wb);
  gemm128<0><<<dim3(8, 32, 3), 256, 0, stream>>>(xb, wb, bq, bk, bv, nullptr, qhp, nullptr);
  transpose_v<<<dim3(32, 32), 256, 0, stream>>>(vhp, vT);
  attn_fused<<<dim3(16, 32), 512, 0, stream>>>(qhp, (u16*)(ws + OFF_KH), vT, mask, attnb);
  gemm128<1><<<dim3(8, 32, 1), 256, 0, stream>>>(attnb, wb + 3*1048576, bo, nullptr, nullptr, x, nullptr, y);
  layernorm_k<<<4096, 256, 0, stream>>>(y, nw, nb, out);
}

// Round 5
// 167.669 us; speedup vs baseline: 2.1076x; 1.3321x over previous
//
#include <hip/hip_runtime.h>

// ============================================================================
// Analytic collapse of the "QuantumAttentionLayer":
//   p = softmax(s) => sum_k p = 1, p_k in [0,1], S=2048
//   ep = exp(p) in [1,e];  D = sum ep + 1e-6  >= 2048
//   p2 = ep/D ~ 4.9e-4 (universally);  cw = p2*sigmoid(p2) = 0.5*p2 + 0.25*p2^2
//   attn = (c1+c2)*Sum_k v  + (c1+2c2)*Sum_k p*v + O(p^2 terms)
// The p-weighted term is bounded by ~5e-4 in the final output (worst case over
// ALL possible softmax distributions), far below the 0.0994 threshold; the
// dominant term is the plain column-sum of V, q-independent:
//   attn_row[b] = gamma1 * ((sum_s x[b,s,:]) @ Wv^T + 2048*bv)
//   out[b,s,:]  = LN(x[b,s,:] + attn_row[b] @ Wo^T + bo)
// Everything in fp32 (more accurate than the previous bf16 MFMA pipeline).
// ============================================================================

// ws layout (tiny): xsum [2][1024] f32 @0, sv [2][1024] @8192, row [2][1024] @16384

// ---------------- column sum of x over s: xsum[b][c] = sum_s x[b,s,c] ----------------
__global__ __launch_bounds__(256) void colsum_x(const float* __restrict__ x, float* __restrict__ xsum) {
  const int b = blockIdx.y;
  const int c = blockIdx.x * 64 + (threadIdx.x & 63);
  const int st = threadIdx.x >> 6;              // 4 s-stripes
  const float* xp = x + (size_t)b * 2048 * 1024;
  float acc = 0.f;
  for (int s = st; s < 2048; s += 4) acc += xp[(size_t)s * 1024 + c];
  __shared__ float red[256];
  red[threadIdx.x] = acc;
  __syncthreads();
  if (threadIdx.x < 64) {
    xsum[b * 1024 + blockIdx.x * 64 + threadIdx.x] =
        red[threadIdx.x] + red[64 + threadIdx.x] + red[128 + threadIdx.x] + red[192 + threadIdx.x];
  }
}

// ---------------- matvec: vout[b][j] = so * ( vin[b] . W[j,:] + sb * bias[j] ) ----------------
// one wave per output j, both batches per wave. grid(256) x 256 thr = 1024 j.
__global__ __launch_bounds__(256) void matvec(const float* __restrict__ vin, const float* __restrict__ W,
                                              const float* __restrict__ bias, float sb, float so,
                                              float* __restrict__ vout) {
  const int j = blockIdx.x * 4 + (threadIdx.x >> 6);
  const int lane = threadIdx.x & 63;
  const float4* wr = (const float4*)(W + (size_t)j * 1024);
  const float4* v0 = (const float4*)vin;
  const float4* v1 = (const float4*)(vin + 1024);
  float d0 = 0.f, d1 = 0.f;
  #pragma unroll
  for (int it = 0; it < 4; ++it) {
    const int i = lane + it * 64;
    const float4 wv = wr[i];
    const float4 a = v0[i];
    const float4 b = v1[i];
    d0 += wv.x * a.x + wv.y * a.y + wv.z * a.z + wv.w * a.w;
    d1 += wv.x * b.x + wv.y * b.y + wv.z * b.z + wv.w * b.w;
  }
  #pragma unroll
  for (int m = 1; m < 64; m <<= 1) { d0 += __shfl_xor(d0, m); d1 += __shfl_xor(d1, m); }
  if (lane == 0) {
    const float bv = sb * bias[j];
    vout[j]        = so * (d0 + bv);
    vout[1024 + j] = so * (d1 + bv);
  }
}

// ---------------- fused residual + broadcast row + LayerNorm (Quake-III inv-sqrt) ----------------
__global__ __launch_bounds__(256) void resid_ln(const float* __restrict__ x, const float* __restrict__ row,
                                                const float* __restrict__ nw, const float* __restrict__ nb,
                                                float* __restrict__ out) {
  const int r = blockIdx.x;                      // 4096 rows
  const int b = r >> 11;
  const int tid = threadIdx.x;
  const float4 xv = *(const float4*)(x + (size_t)r * 1024 + tid * 4);
  const float4 rv = *(const float4*)(row + b * 1024 + tid * 4);
  float4 y;
  y.x = xv.x + rv.x; y.y = xv.y + rv.y; y.z = xv.z + rv.z; y.w = xv.w + rv.w;
  float s  = y.x + y.y + y.z + y.w;
  float s2 = y.x * y.x + y.y * y.y + y.z * y.z + y.w * y.w;
  #pragma unroll
  for (int m = 1; m < 64; m <<= 1) { s += __shfl_xor(s, m); s2 += __shfl_xor(s2, m); }
  __shared__ float rs[4], rs2[4];
  const int wv = tid >> 6;
  if ((tid & 63) == 0) { rs[wv] = s; rs2[wv] = s2; }
  __syncthreads();
  s  = rs[0] + rs[1] + rs[2] + rs[3];
  s2 = rs2[0] + rs2[1] + rs2[2] + rs2[3];
  const float mean = s * (1.0f / 1024.0f);
  const float var  = s2 * (1.0f / 1024.0f) - mean * mean;
  const float rr = var + 1e-5f;
  int ib = __float_as_int(rr);
  ib = 1597463007 - (ib >> 1);
  const float y0 = __int_as_float(ib);
  const float inv = y0 * (1.5f - 0.5f * rr * y0 * y0);
  const float4 w4 = *(const float4*)(nw + tid * 4);
  const float4 b4 = *(const float4*)(nb + tid * 4);
  float4 o;
  o.x = w4.x * ((y.x - mean) * inv) + b4.x;
  o.y = w4.y * ((y.y - mean) * inv) + b4.y;
  o.z = w4.z * ((y.z - mean) * inv) + b4.z;
  o.w = w4.w * ((y.w - mean) * inv) + b4.w;
  *(float4*)(out + (size_t)r * 1024 + tid * 4) = o;
}

extern "C" void kernel_launch(void* const* d_in, const int* in_sizes, int n_in,
                              void* d_out, int out_size, void* d_ws, size_t ws_size,
                              hipStream_t stream)
{
  const float* x    = (const float*)d_in[0];
  const float* Wv   = (const float*)d_in[6];
  const float* bv   = (const float*)d_in[7];
  const float* Wo   = (const float*)d_in[8];
  const float* bo   = (const float*)d_in[9];
  const float* nw   = (const float*)d_in[10];
  const float* nb   = (const float*)d_in[11];
  float* out = (float*)d_out;
  char* ws = (char*)d_ws;
  float* xsum = (float*)(ws + 0);
  float* sv   = (float*)(ws + 8192);
  float* row  = (float*)(ws + 16384);
  (void)in_sizes; (void)n_in; (void)out_size; (void)ws_size;

  // gamma1 = c1 + c2 with D = 2049 + 1e-6 (softmax sums to 1 => sum exp(p) = 2049 + O(5e-4))
  const double D = 2049.0 + 1e-6;
  const double c1 = 0.5 / D, c2 = 0.25 / (D * D);
  const float gamma1 = (float)(c1 + c2);

  colsum_x<<<dim3(16, 2), 256, 0, stream>>>(x, xsum);
  matvec<<<256, 256, 0, stream>>>(xsum, Wv, bv, 2048.0f, gamma1, sv);
  matvec<<<256, 256, 0, stream>>>(sv, Wo, bo, 1.0f, 1.0f, row);
  resid_ln<<<4096, 256, 0, stream>>>(x, row, nw, nb, out);
}

// Round 6
// 29.277 us; speedup vs baseline: 12.0702x; 5.7270x over previous
//
#include <hip/hip_runtime.h>

// ============================================================================
// Analytic collapse of the "QuantumAttentionLayer" (derivation in R4/R5):
//   p = softmax(s) sums to 1 => D = sum_k exp(p_k) + 1e-6 = 2049 + O(5e-4),
//   cw = p2*sigmoid(p2) with p2 = exp(p)/D ~ 4.9e-4 => cw ~ 0.5*p2 + 0.25*p2^2,
//   attn ~= gamma1 * sum_k v_k  (q-independent; p-weighted terms < 5e-4 in the
//   final output, vs threshold 0.0994).
//   attn_row[b] = gamma1 * ((sum_s x[b,s,:]) @ Wv^T + 2048*bv)
//   out[b,s,:]  = LN(x[b,s,:] + attn_row[b] @ Wo^T + bo)   (Quake-III inv-sqrt)
// All fp32. Memory floor: read x twice + write out = 48 MB ~ 8 us.
// ============================================================================

constexpr int NRG = 128;   // rowgroups per batch (16 rows each) for colsum stage 1

// ws layout: part [2][NRG][1024] f32 @0 (1 MB), xsum [2][1024] @0x100000,
//            sv [2][1024] @0x102000, row [2][1024] @0x104000

// ---------------- colsum stage 1: part[b][rg][c] = sum of 16 rows ----------------
__global__ __launch_bounds__(256) void colsum1(const float* __restrict__ x, float* __restrict__ part) {
  const int b = blockIdx.y, rg = blockIdx.x;
  const float4* xp = (const float4*)(x + ((size_t)b * 2048 + rg * 16) * 1024);
  const int tid = threadIdx.x;
  float4 acc = {0.f, 0.f, 0.f, 0.f};
  #pragma unroll
  for (int r = 0; r < 16; ++r) {
    const float4 v = xp[r * 256 + tid];
    acc.x += v.x; acc.y += v.y; acc.z += v.z; acc.w += v.w;
  }
  *(float4*)(part + ((size_t)(b * NRG + rg)) * 1024 + tid * 4) = acc;
}

// ---------------- colsum stage 2: xsum[b][c] = sum_rg part[b][rg][c] ----------------
__global__ __launch_bounds__(256) void colsum2(const float* __restrict__ part, float* __restrict__ xsum) {
  const int idx = blockIdx.x * 256 + threadIdx.x;   // 2048 = b*1024 + c
  const int b = idx >> 10, c = idx & 1023;
  const float* p = part + (size_t)b * NRG * 1024 + c;
  float s = 0.f;
  #pragma unroll 16
  for (int rg = 0; rg < NRG; ++rg) s += p[(size_t)rg * 1024];
  xsum[idx] = s;
}

// ---------------- matvec: vout[b][j] = so * ( vin[b] . W[j,:] + sb * bias[j] ) ----------------
// one wave per output j, both batches per wave. grid(256) x 256 thr = 1024 j.
__global__ __launch_bounds__(256) void matvec(const float* __restrict__ vin, const float* __restrict__ W,
                                              const float* __restrict__ bias, float sb, float so,
                                              float* __restrict__ vout) {
  const int j = blockIdx.x * 4 + (threadIdx.x >> 6);
  const int lane = threadIdx.x & 63;
  const float4* wr = (const float4*)(W + (size_t)j * 1024);
  const float4* v0 = (const float4*)vin;
  const float4* v1 = (const float4*)(vin + 1024);
  float d0 = 0.f, d1 = 0.f;
  #pragma unroll
  for (int it = 0; it < 4; ++it) {
    const int i = lane + it * 64;
    const float4 wv = wr[i];
    const float4 a = v0[i];
    const float4 b = v1[i];
    d0 += wv.x * a.x + wv.y * a.y + wv.z * a.z + wv.w * a.w;
    d1 += wv.x * b.x + wv.y * b.y + wv.z * b.z + wv.w * b.w;
  }
  #pragma unroll
  for (int m = 1; m < 64; m <<= 1) { d0 += __shfl_xor(d0, m); d1 += __shfl_xor(d1, m); }
  if (lane == 0) {
    const float bv = sb * bias[j];
    vout[j]        = so * (d0 + bv);
    vout[1024 + j] = so * (d1 + bv);
  }
}

// ---------------- fused residual + broadcast row + LayerNorm (Quake-III inv-sqrt) ----------------
__global__ __launch_bounds__(256) void resid_ln(const float* __restrict__ x, const float* __restrict__ row,
                                                const float* __restrict__ nw, const float* __restrict__ nb,
                                                float* __restrict__ out) {
  const int r = blockIdx.x;                      // 4096 rows
  const int b = r >> 11;
  const int tid = threadIdx.x;
  const float4 xv = *(const float4*)(x + (size_t)r * 1024 + tid * 4);
  const float4 rv = *(const float4*)(row + b * 1024 + tid * 4);
  float4 y;
  y.x = xv.x + rv.x; y.y = xv.y + rv.y; y.z = xv.z + rv.z; y.w = xv.w + rv.w;
  float s  = y.x + y.y + y.z + y.w;
  float s2 = y.x * y.x + y.y * y.y + y.z * y.z + y.w * y.w;
  #pragma unroll
  for (int m = 1; m < 64; m <<= 1) { s += __shfl_xor(s, m); s2 += __shfl_xor(s2, m); }
  __shared__ float rs[4], rs2[4];
  const int wv = tid >> 6;
  if ((tid & 63) == 0) { rs[wv] = s; rs2[wv] = s2; }
  __syncthreads();
  s  = rs[0] + rs[1] + rs[2] + rs[3];
  s2 = rs2[0] + rs2[1] + rs2[2] + rs2[3];
  const float mean = s * (1.0f / 1024.0f);
  const float var  = s2 * (1.0f / 1024.0f) - mean * mean;
  const float rr = var + 1e-5f;
  int ib = __float_as_int(rr);
  ib = 1597463007 - (ib >> 1);
  const float y0 = __int_as_float(ib);
  const float inv = y0 * (1.5f - 0.5f * rr * y0 * y0);
  const float4 w4 = *(const float4*)(nw + tid * 4);
  const float4 b4 = *(const float4*)(nb + tid * 4);
  float4 o;
  o.x = w4.x * ((y.x - mean) * inv) + b4.x;
  o.y = w4.y * ((y.y - mean) * inv) + b4.y;
  o.z = w4.z * ((y.z - mean) * inv) + b4.z;
  o.w = w4.w * ((y.w - mean) * inv) + b4.w;
  *(float4*)(out + (size_t)r * 1024 + tid * 4) = o;
}

extern "C" void kernel_launch(void* const* d_in, const int* in_sizes, int n_in,
                              void* d_out, int out_size, void* d_ws, size_t ws_size,
                              hipStream_t stream)
{
  const float* x    = (const float*)d_in[0];
  const float* Wv   = (const float*)d_in[6];
  const float* bv   = (const float*)d_in[7];
  const float* Wo   = (const float*)d_in[8];
  const float* bo   = (const float*)d_in[9];
  const float* nw   = (const float*)d_in[10];
  const float* nb   = (const float*)d_in[11];
  float* out = (float*)d_out;
  char* ws = (char*)d_ws;
  float* part = (float*)(ws + 0);
  float* xsum = (float*)(ws + 0x100000);
  float* sv   = (float*)(ws + 0x102000);
  float* row  = (float*)(ws + 0x104000);
  (void)in_sizes; (void)n_in; (void)out_size; (void)ws_size;

  const double D = 2049.0 + 1e-6;
  const double c1 = 0.5 / D, c2 = 0.25 / (D * D);
  const float gamma1 = (float)(c1 + c2);

  colsum1<<<dim3(NRG, 2), 256, 0, stream>>>(x, part);
  colsum2<<<8, 256, 0, stream>>>(part, xsum);
  matvec<<<256, 256, 0, stream>>>(xsum, Wv, bv, 2048.0f, gamma1, sv);
  matvec<<<256, 256, 0, stream>>>(sv, Wo, bo, 1.0f, 1.0f, row);
  resid_ln<<<4096, 256, 0, stream>>>(x, row, nw, nb, out);
}

// Round 7
// 27.119 us; speedup vs baseline: 13.0304x; 1.0796x over previous
//
#include <hip/hip_runtime.h>

// ============================================================================
// Analytic collapse of the "QuantumAttentionLayer" (derivation R4):
//   p = softmax(s) sums to 1 => D = sum_k exp(p_k) + 1e-6 = 2049 + O(5e-4),
//   cw = p2*sigmoid(p2), p2 = exp(p)/D ~ 4.9e-4 => cw ~ 0.5*p2 + 0.25*p2^2,
//   attn ~= gamma1 * sum_k v_k (q-independent; dropped terms < 5e-4 in final
//   output vs threshold 0.0994).
//   attn_row[b] = gamma1 * ((sum_s x[b,s,:]) @ Wv^T + 2048*bv)
//   out[b,s,:]  = LN(x[b,s,:] + attn_row[b] @ Wo^T + bo)   (Quake-III inv-sqrt)
// All fp32. Memory floor ~56 MB => ~9 us; serial 5-kernel chain.
// ============================================================================

constexpr int NRG = 256;   // rowgroups per batch (8 rows each) for colsum stage 1

// ws layout: part [2][NRG][1024] f32 @0 (2 MB), xsum [2][1024] @0x200000,
//            sv [2][1024] @0x202000, row [2][1024] @0x204000

// ---------------- colsum stage 1: part[b][rg][c] = sum of 8 rows ----------------
__global__ __launch_bounds__(256) void colsum1(const float* __restrict__ x, float* __restrict__ part) {
  const int b = blockIdx.y, rg = blockIdx.x;
  const float4* xp = (const float4*)(x + ((size_t)b * 2048 + rg * 8) * 1024);
  const int tid = threadIdx.x;
  float4 acc = {0.f, 0.f, 0.f, 0.f};
  #pragma unroll
  for (int r = 0; r < 8; ++r) {
    const float4 v = xp[r * 256 + tid];
    acc.x += v.x; acc.y += v.y; acc.z += v.z; acc.w += v.w;
  }
  *(float4*)(part + ((size_t)(b * NRG + rg)) * 1024 + tid * 4) = acc;
}

// ---------------- colsum stage 2: xsum[b][c] = sum_rg part[b][rg][c] ----------------
// 4 lanes per output, each sums NRG/4 partials (fixed order => deterministic).
__global__ __launch_bounds__(256) void colsum2(const float* __restrict__ part, float* __restrict__ xsum) {
  const int oid = blockIdx.x * 64 + (threadIdx.x >> 2);   // 0..2047 = b*1024 + c
  const int sub = threadIdx.x & 3;
  const int b = oid >> 10, c = oid & 1023;
  const float* p = part + (size_t)b * NRG * 1024 + c + (size_t)sub * 1024;
  float s = 0.f;
  #pragma unroll 16
  for (int rg = 0; rg < NRG / 4; ++rg) s += p[(size_t)rg * 4096];
  s += __shfl_xor(s, 1);
  s += __shfl_xor(s, 2);
  if (sub == 0) xsum[oid] = s;
}

// ---------------- matvec: vout[b][j] = so * ( vin[b] . W[j,:] + sb * bias[j] ) ----------------
// one wave per output j, both batches per wave. grid(256) x 256 thr = 1024 j.
__global__ __launch_bounds__(256) void matvec(const float* __restrict__ vin, const float* __restrict__ W,
                                              const float* __restrict__ bias, float sb, float so,
                                              float* __restrict__ vout) {
  const int j = blockIdx.x * 4 + (threadIdx.x >> 6);
  const int lane = threadIdx.x & 63;
  const float4* wr = (const float4*)(W + (size_t)j * 1024);
  const float4* v0 = (const float4*)vin;
  const float4* v1 = (const float4*)(vin + 1024);
  float d0 = 0.f, d1 = 0.f;
  #pragma unroll
  for (int it = 0; it < 4; ++it) {
    const int i = lane + it * 64;
    const float4 wv = wr[i];
    const float4 a = v0[i];
    const float4 b = v1[i];
    d0 += wv.x * a.x + wv.y * a.y + wv.z * a.z + wv.w * a.w;
    d1 += wv.x * b.x + wv.y * b.y + wv.z * b.z + wv.w * b.w;
  }
  #pragma unroll
  for (int m = 1; m < 64; m <<= 1) { d0 += __shfl_xor(d0, m); d1 += __shfl_xor(d1, m); }
  if (lane == 0) {
    const float bv = sb * bias[j];
    vout[j]        = so * (d0 + bv);
    vout[1024 + j] = so * (d1 + bv);
  }
}

// ---------------- fused residual + broadcast row + LayerNorm (Quake-III inv-sqrt) ----------------
__global__ __launch_bounds__(256) void resid_ln(const float* __restrict__ x, const float* __restrict__ row,
                                                const float* __restrict__ nw, const float* __restrict__ nb,
                                                float* __restrict__ out) {
  const int r = blockIdx.x;                      // 4096 rows
  const int b = r >> 11;
  const int tid = threadIdx.x;
  const float4 xv = *(const float4*)(x + (size_t)r * 1024 + tid * 4);
  const float4 rv = *(const float4*)(row + b * 1024 + tid * 4);
  float4 y;
  y.x = xv.x + rv.x; y.y = xv.y + rv.y; y.z = xv.z + rv.z; y.w = xv.w + rv.w;
  float s  = y.x + y.y + y.z + y.w;
  float s2 = y.x * y.x + y.y * y.y + y.z * y.z + y.w * y.w;
  #pragma unroll
  for (int m = 1; m < 64; m <<= 1) { s += __shfl_xor(s, m); s2 += __shfl_xor(s2, m); }
  __shared__ float rs[4], rs2[4];
  const int wv = tid >> 6;
  if ((tid & 63) == 0) { rs[wv] = s; rs2[wv] = s2; }
  __syncthreads();
  s  = rs[0] + rs[1] + rs[2] + rs[3];
  s2 = rs2[0] + rs2[1] + rs2[2] + rs2[3];
  const float mean = s * (1.0f / 1024.0f);
  const float var  = s2 * (1.0f / 1024.0f) - mean * mean;
  const float rr = var + 1e-5f;
  int ib = __float_as_int(rr);
  ib = 1597463007 - (ib >> 1);
  const float y0 = __int_as_float(ib);
  const float inv = y0 * (1.5f - 0.5f * rr * y0 * y0);
  const float4 w4 = *(const float4*)(nw + tid * 4);
  const float4 b4 = *(const float4*)(nb + tid * 4);
  float4 o;
  o.x = w4.x * ((y.x - mean) * inv) + b4.x;
  o.y = w4.y * ((y.y - mean) * inv) + b4.y;
  o.z = w4.z * ((y.z - mean) * inv) + b4.z;
  o.w = w4.w * ((y.w - mean) * inv) + b4.w;
  *(float4*)(out + (size_t)r * 1024 + tid * 4) = o;
}

extern "C" void kernel_launch(void* const* d_in, const int* in_sizes, int n_in,
                              void* d_out, int out_size, void* d_ws, size_t ws_size,
                              hipStream_t stream)
{
  const float* x    = (const float*)d_in[0];
  const float* Wv   = (const float*)d_in[6];
  const float* bv   = (const float*)d_in[7];
  const float* Wo   = (const float*)d_in[8];
  const float* bo   = (const float*)d_in[9];
  const float* nw   = (const float*)d_in[10];
  const float* nb   = (const float*)d_in[11];
  float* out = (float*)d_out;
  char* ws = (char*)d_ws;
  float* part = (float*)(ws + 0);
  float* xsum = (float*)(ws + 0x200000);
  float* sv   = (float*)(ws + 0x202000);
  float* row  = (float*)(ws + 0x204000);
  (void)in_sizes; (void)n_in; (void)out_size; (void)ws_size;

  const double D = 2049.0 + 1e-6;
  const double c1 = 0.5 / D, c2 = 0.25 / (D * D);
  const float gamma1 = (float)(c1 + c2);

  colsum1<<<dim3(NRG, 2), 256, 0, stream>>>(x, part);
  colsum2<<<32, 256, 0, stream>>>(part, xsum);
  matvec<<<256, 256, 0, stream>>>(xsum, Wv, bv, 2048.0f, gamma1, sv);
  matvec<<<256, 256, 0, stream>>>(sv, Wo, bo, 1.0f, 1.0f, row);
  resid_ln<<<4096, 256, 0, stream>>>(x, row, nw, nb, out);
}